// Round 6
// baseline (497.839 us; speedup 1.0000x reference)
//
#include <hip/hip_runtime.h>

// ---------------------------------------------------------------------------
// QuantizedAttention: x[B,S,D] -> QKV proj (int8-quant wts) -> RMSNorm -> RoPE
//   -> causal GQA attention -> O proj.  B=2 S=2048 D=2048 H=16 KVH=8 HD=128.
// R6: GEMMs rewritten as register-streaming (zero-LDS, zero-barrier K-loop):
// A and B pre-packed into MFMA fragment order so every fragment is one
// coalesced 1KB global_load_dwordx4; compiler software-pipelines with
// fine-grained vmcnt (the AITER pattern). Epilogue fusions kept from R5.
// attn unchanged from R4/R5.
// ---------------------------------------------------------------------------

typedef __attribute__((ext_vector_type(4))) float floatx4;
typedef __attribute__((ext_vector_type(8))) short short8v;
typedef __attribute__((ext_vector_type(4))) short short4v;
typedef __attribute__((ext_vector_type(8))) unsigned short ushort8v;

#define DEVINL __device__ __forceinline__

constexpr int cB = 2, cS = 2048, cD = 2048, cH = 16, cKVH = 8, cHD = 128;
constexpr int cM = cB * cS;
constexpr int cNqkv = (cH + 2 * cKVH) * cHD;
constexpr float cEPS = 1e-6f;
constexpr float cSCALE = 0.08838834764831845f;   // 1/sqrt(HD)

DEVINL unsigned short f2bf(float f) {
  unsigned u = __float_as_uint(f);
  unsigned r = ((u >> 16) & 1u) + 0x7FFFu;
  return (unsigned short)((u + r) >> 16);
}
DEVINL float bf2f(unsigned short h) { return __uint_as_float(((unsigned)h) << 16); }

DEVINL floatx4 mfma_bf16(short8v a, short8v b, floatx4 c) {
  return __builtin_amdgcn_mfma_f32_16x16x32_bf16(a, b, c, 0, 0, 0);
}

DEVINL floatx4 mfma_pv(short4v a, short4v b, floatx4 c) {
#if __has_builtin(__builtin_amdgcn_mfma_f32_16x16x16bf16_1k)
  return __builtin_amdgcn_mfma_f32_16x16x16bf16_1k(a, b, c, 0, 0, 0);
#else
  short8v a8 = {a[0], a[1], a[2], a[3], (short)0, (short)0, (short)0, (short)0};
  short8v b8 = {b[0], b[1], b[2], b[3], (short)0, (short)0, (short)0, (short)0};
  return __builtin_amdgcn_mfma_f32_16x16x32_bf16(a8, b8, c, 0, 0, 0);
#endif
}

DEVINL void gl_lds16(const void* g, void* l) {
  __builtin_amdgcn_global_load_lds(
      (const __attribute__((address_space(1))) void*)g,
      (__attribute__((address_space(3))) void*)l, 16, 0, 0);
}

// --------------------------- dtype detection -------------------------------
__global__ void detect_dtype(const unsigned* __restrict__ x, int* __restrict__ flag) {
  __shared__ int cnt;
  if (threadIdx.x == 0) cnt = 0;
  __syncthreads();
  int c = 0;
  for (int i = threadIdx.x; i < 4096; i += 256) {
    unsigned e = (x[i] >> 7) & 0xFFu;
    c += (e >= 100u && e <= 142u) ? 1 : 0;
  }
  atomicAdd(&cnt, c);
  __syncthreads();
  if (threadIdx.x == 0) *flag = (cnt > 2457) ? 1 : 0;  // 1 = host is bf16
}

// --------------------------- fragment packer -------------------------------
// Packs a row-major [rows][K] matrix into MFMA fragment order:
//   dst[(T*64 + kb)*512 + lane*8 + j] = src[T*16 + (lane&15)][kb*32 + (lane>>4)*8 + j]
// so one global_load_dwordx4 at ((T*64+kb)*512 + lane*8) IS the A/B fragment.
// mode: 0 = float-auto(flag: fp32 or bf16), 2 = int32, 3 = bf16.
__global__ __launch_bounds__(256) void pack_frag(
    const void* __restrict__ src, unsigned short* __restrict__ dst,
    int K, int mode, const int* __restrict__ flag) {
  __shared__ float L[16][264];
  const int T = blockIdx.x, kc = blockIdx.y;
  const int tid = threadIdx.x;
  int md = mode;
  if (md == 0) md = (*flag) ? 3 : 1;
#pragma unroll
  for (int it = 0; it < 16; it++) {
    int e = it * 256 + tid;
    int r = e >> 8, c = e & 255;
    size_t idx = (size_t)(T * 16 + r) * K + kc * 256 + c;
    float v;
    if (md == 1)      v = ((const float*)src)[idx];
    else if (md == 2) v = (float)((const int*)src)[idx];
    else              v = bf2f(((const unsigned short*)src)[idx]);
    L[r][c] = v;
  }
  __syncthreads();
  const int lane = tid & 63, w = tid >> 6;
  const int q = lane >> 4, l16 = lane & 15;
#pragma unroll
  for (int p = 0; p < 2; p++) {
    int kbl = w + p * 4;
    ushort8v o;
#pragma unroll
    for (int j = 0; j < 8; j++) o[j] = f2bf(L[l16][kbl * 32 + q * 8 + j]);
    *(ushort8v*)(dst + ((size_t)T * 64 + kc * 8 + kbl) * 512 + lane * 8) = o;
  }
}

__global__ void conv_f32(const void* __restrict__ src, float* __restrict__ dst,
                         int n, const int* __restrict__ flag) {
  int i = blockIdx.x * 256 + threadIdx.x;
  if (i >= n) return;
  dst[i] = (*flag) ? bf2f(((const unsigned short*)src)[i]) : ((const float*)src)[i];
}

// Packed RoPE table: tab[s*64+t] = {cos[s,t], sin[s,t]} for t<64 (halves equal).
__global__ void rope_pack(const void* __restrict__ cosc, const void* __restrict__ sinc,
                          float2* __restrict__ tab, const int* __restrict__ flag) {
  int i = blockIdx.x * 256 + threadIdx.x;
  if (i >= cS * 64) return;
  int s = i >> 6, t = i & 63;
  int f = *flag;
  float c = f ? bf2f(((const unsigned short*)cosc)[s * cHD + t])
              : ((const float*)cosc)[s * cHD + t];
  float sn = f ? bf2f(((const unsigned short*)sinc)[s * cHD + t])
               : ((const float*)sinc)[s * cHD + t];
  tab[i] = make_float2(c, sn);
}

// --------------------------- register-streaming GEMM core ------------------
// Wave computes a 64x64 tile (4x4 of 16x16x32 MFMA) streaming fragments
// straight from packed global layout into VGPRs. No LDS, no barriers:
// phase-ping-pong register double buffer, prefetch distance = 1 k-block.
DEVINL void gemm_core_rr(const unsigned short* __restrict__ Ap,
                         const unsigned short* __restrict__ Bp,
                         int tm0, int tn0, int nkb, int lane,
                         floatx4 acc[4][4]) {
  const unsigned short* ap[4];
  const unsigned short* bp[4];
#pragma unroll
  for (int i = 0; i < 4; i++) {
    ap[i] = Ap + ((size_t)(tm0 + i) * 64) * 512 + lane * 8;
    bp[i] = Bp + ((size_t)(tn0 + i) * 64) * 512 + lane * 8;
  }
  short8v a0[4], b0[4], a1[4], b1[4];
#pragma unroll
  for (int i = 0; i < 4; i++) {
    a0[i] = *(const short8v*)(ap[i]);
    b0[i] = *(const short8v*)(bp[i]);
  }
  for (int kb = 0; kb < nkb; kb += 2) {
    const int o1 = (kb + 1) * 512;
#pragma unroll
    for (int i = 0; i < 4; i++) {
      a1[i] = *(const short8v*)(ap[i] + o1);
      b1[i] = *(const short8v*)(bp[i] + o1);
    }
#pragma unroll
    for (int mt = 0; mt < 4; mt++)
#pragma unroll
      for (int nt = 0; nt < 4; nt++)
        acc[mt][nt] = mfma_bf16(a0[mt], b0[nt], acc[mt][nt]);
    if (kb + 2 < nkb) {
      const int o2 = (kb + 2) * 512;
#pragma unroll
      for (int i = 0; i < 4; i++) {
        a0[i] = *(const short8v*)(ap[i] + o2);
        b0[i] = *(const short8v*)(bp[i] + o2);
      }
    }
#pragma unroll
    for (int mt = 0; mt < 4; mt++)
#pragma unroll
      for (int nt = 0; nt < 4; nt++)
        acc[mt][nt] = mfma_bf16(a1[mt], b1[nt], acc[mt][nt]);
  }
}

// ------------------- fused QKV GEMM + RMSNorm + RoPE + V^T -----------------
__global__ __launch_bounds__(256) void gemm_qkv(
    const unsigned short* __restrict__ Ap, const unsigned short* __restrict__ Bp,
    const float* __restrict__ colscale, const float2* __restrict__ ropetab,
    const float* __restrict__ nw, unsigned short* __restrict__ Qb,
    unsigned short* __restrict__ Kb, unsigned short* __restrict__ Vt) {
  __shared__ float4 smem4[2192];            // 35072 B (epilogue only)
  char* smem = (char*)smem4;
  const int tid = threadIdx.x;
  const int lane = tid & 63, wave = tid >> 6;
  const int q = lane >> 4, l16 = lane & 15;
  const int m0 = blockIdx.y * 128, n0 = blockIdx.x * 128;
  const int wm = (wave & 1) * 64, wn = (wave >> 1) * 64;

  floatx4 acc[4][4] = {};
  gemm_core_rr(Ap, Bp, (m0 + wm) >> 4, (n0 + wn) >> 4, cD / 32, lane, acc);

  // ---- epilogue (validated R5) ----
  float sc[4];
#pragma unroll
  for (int nt = 0; nt < 4; nt++) sc[nt] = colscale[n0 + wn + nt * 16 + l16];
#pragma unroll
  for (int mt = 0; mt < 4; mt++)
#pragma unroll
    for (int nt = 0; nt < 4; nt++)
#pragma unroll
      for (int rg = 0; rg < 4; rg++) acc[mt][nt][rg] *= sc[nt];

  const int tile_n = blockIdx.x;
  const int bi = m0 >> 11, sbase = m0 & (cS - 1);

  if (tile_n >= 24) {
    // V: transpose through LDS, store Vt[.,d,s]
    unsigned short* T = (unsigned short*)smem;   // [128 d][136 s]
#pragma unroll
    for (int mt = 0; mt < 4; mt++)
#pragma unroll
      for (int nt = 0; nt < 4; nt++) {
        short4v pk;
#pragma unroll
        for (int rg = 0; rg < 4; rg++) pk[rg] = (short)f2bf(acc[mt][nt][rg]);
        *(short4v*)(T + (wn + nt * 16 + l16) * 136 + (wm + mt * 16 + q * 4)) = pk;
      }
    __syncthreads();
    const int d = tid >> 1, sh = (tid & 1) * 64;
    unsigned short* dst = Vt + ((size_t)(bi * cKVH + (tile_n - 24)) * cHD + d) * cS
                          + sbase + sh;
#pragma unroll
    for (int j = 0; j < 8; j++)
      *(ushort8v*)(dst + j * 8) = *(const ushort8v*)(T + d * 136 + sh + j * 8);
  } else {
    // Q/K: RMSNorm + RoPE
    unsigned short* W = (unsigned short*)smem;   // 4 waves x 4096 ushorts
    float* ssq  = (float*)(smem + 32768);        // [2][128]
    float* invs = (float*)(smem + 33792);        // [128]

    float sl[4][4];
#pragma unroll
    for (int mt = 0; mt < 4; mt++)
#pragma unroll
      for (int rg = 0; rg < 4; rg++) {
        float s = 0.f;
#pragma unroll
        for (int nt = 0; nt < 4; nt++) s += acc[mt][nt][rg] * acc[mt][nt][rg];
        s += __shfl_xor(s, 1); s += __shfl_xor(s, 2);
        s += __shfl_xor(s, 4); s += __shfl_xor(s, 8);
        sl[mt][rg] = s;
      }
    unsigned short* Wo = W + wave * 4096;
#pragma unroll
    for (int mt = 0; mt < 4; mt++)
#pragma unroll
      for (int nt = 0; nt < 4; nt++) {
        short4v pk;
#pragma unroll
        for (int rg = 0; rg < 4; rg++) pk[rg] = (short)f2bf(acc[mt][nt][rg]);
        *(short4v*)(Wo + (mt * 4 + nt) * 256 + lane * 4) = pk;
      }
    if (l16 == 0) {
#pragma unroll
      for (int mt = 0; mt < 4; mt++)
#pragma unroll
        for (int rg = 0; rg < 4; rg++)
          ssq[((wave >> 1) & 1) * 128 + wm + mt * 16 + q * 4 + rg] = sl[mt][rg];
    }
    __syncthreads();
    if (tid < 128)
      invs[tid] = rsqrtf((ssq[tid] + ssq[128 + tid]) * (1.0f / cHD) + cEPS);
    __syncthreads();

    const unsigned short* Wp = W + (wave ^ 2) * 4096;
    const int wn1 = wave >> 1;
    const float* nwb = nw + (tile_n < 16 ? 0 : cHD);
    float wown[4], wpar[4];
#pragma unroll
    for (int nt = 0; nt < 4; nt++) {
      wown[nt] = nwb[wn1 * 64 + nt * 16 + l16];
      wpar[nt] = nwb[(wn1 ^ 1) * 64 + nt * 16 + l16];
    }
    unsigned short* dstb = (tile_n < 16)
        ? Qb + ((size_t)(bi * cH + tile_n) * cS) * cHD
        : Kb + ((size_t)(bi * cKVH + (tile_n - 16)) * cS) * cHD;
#pragma unroll
    for (int mt = 0; mt < 4; mt++) {
      float iv[4];
#pragma unroll
      for (int rg = 0; rg < 4; rg++) iv[rg] = invs[wm + mt * 16 + q * 4 + rg];
#pragma unroll
      for (int nt = 0; nt < 4; nt++) {
        short4v pk = *(const short4v*)(Wp + (mt * 4 + nt) * 256 + lane * 4);
#pragma unroll
        for (int rg = 0; rg < 4; rg++) {
          int srow = sbase + wm + mt * 16 + q * 4 + rg;
          float2 cs = ropetab[srow * 64 + nt * 16 + l16];
          float nown = acc[mt][nt][rg] * iv[rg] * wown[nt];
          float npar = bf2f((unsigned short)pk[rg]) * iv[rg] * wpar[nt];
          float o = wn1 == 0 ? nown * cs.x - npar * cs.y
                             : nown * cs.x + npar * cs.y;
          dstb[(size_t)srow * cHD + wn1 * 64 + nt * 16 + l16] = f2bf(o);
        }
      }
    }
  }
}

// ------------------- O-proj GEMM with fused flag-output --------------------
__global__ __launch_bounds__(256) void gemm_out(
    const unsigned short* __restrict__ Ap, const unsigned short* __restrict__ Bp,
    const float* __restrict__ colscale, void* __restrict__ Cout,
    const int* __restrict__ flag, int N, int nkb) {
  const int tid = threadIdx.x;
  const int lane = tid & 63, wave = tid >> 6;
  const int q = lane >> 4, l16 = lane & 15;
  const int m0 = blockIdx.y * 128, n0 = blockIdx.x * 128;
  const int wm = (wave & 1) * 64, wn = (wave >> 1) * 64;

  floatx4 acc[4][4] = {};
  gemm_core_rr(Ap, Bp, (m0 + wm) >> 4, (n0 + wn) >> 4, nkb, lane, acc);

  const int f = *flag;
#pragma unroll
  for (int mt = 0; mt < 4; mt++) {
    int r0 = m0 + wm + mt * 16 + q * 4;
#pragma unroll
    for (int nt = 0; nt < 4; nt++) {
      int cn = n0 + wn + nt * 16 + l16;
      float sc = colscale[cn];
#pragma unroll
      for (int rg = 0; rg < 4; rg++) {
        float v = acc[mt][nt][rg] * sc;
        if (f) ((unsigned short*)Cout)[(size_t)(r0 + rg) * N + cn] = f2bf(v);
        else   ((float*)Cout)[(size_t)(r0 + rg) * N + cn] = v;
      }
    }
  }
}

// --------------------------- flash attention (v4, unchanged) ---------------
__global__ __launch_bounds__(256, 2) void attn(
    const unsigned short* __restrict__ Qb, const unsigned short* __restrict__ Kb,
    const unsigned short* __restrict__ Vt, unsigned short* __restrict__ AO) {
  __shared__ unsigned short SM[32768];
  const int tid = threadIdx.x;
  const int lane = tid & 63, wv = tid >> 6;
  const int q = lane >> 4, l16 = lane & 15;
  const int bi = blockIdx.z, h = blockIdx.y;
  const int kh = h >> 1;
  const int qt = (int)gridDim.x - 1 - (int)blockIdx.x;
  const int q0 = qt * 64;
  const int q0w = q0 + wv * 16;

  const unsigned short* Qbase = Qb + ((size_t)(bi * cH + h) * cS + q0w) * cHD;
  const unsigned short* Kbase = Kb + ((size_t)(bi * cKVH + kh) * cS) * cHD;
  const unsigned short* Vbase = Vt + ((size_t)(bi * cKVH + kh) * cHD) * cS;

  short8v qa[4];
#pragma unroll
  for (int c = 0; c < 4; c++)
    qa[c] = *(const short8v*)(Qbase + (size_t)l16 * cHD + c * 32 + q * 8);

  floatx4 oacc[8] = {};
  float lp = 0.f;

  int koff[4], voff[4];
#pragma unroll
  for (int i = 0; i < 4; i++) {
    int s = (wv * 4 + i) * 64 + lane;
    int r = s >> 4, u = (s & 15) ^ (r & 15);
    koff[i] = r * cHD + u * 8;
    int d = s >> 3, uv = (s & 7) ^ (d & 7);
    voff[i] = d * cS + uv * 8;
  }

  auto stage = [&](int win) {
    const int buf = (win & 1) * 16384;
    const int kv0 = win * 64;
    unsigned short* Kdst = SM + buf + (wv * 4) * 512;
    unsigned short* Vdst = SM + buf + 8192 + (wv * 4) * 512;
#pragma unroll
    for (int i = 0; i < 4; i++)
      gl_lds16(Kbase + (size_t)kv0 * cHD + koff[i], Kdst + i * 512);
#pragma unroll
    for (int i = 0; i < 4; i++)
      gl_lds16(Vbase + (size_t)kv0 + voff[i], Vdst + i * 512);
  };

  stage(0);
  for (int win = 0; win <= qt; win++) {
    __syncthreads();
    if (win < qt) stage(win + 1);
    const unsigned short* Ks = SM + (win & 1) * 16384;
    const unsigned short* Vs = Ks + 8192;

    floatx4 sres[4] = {};
#pragma unroll
    for (int c = 0; c < 4; c++) {
      short8v kf[4];
#pragma unroll
      for (int ntk = 0; ntk < 4; ntk++)
        kf[ntk] = *(const short8v*)(Ks + (ntk * 16 + l16) * 128 + (((c * 4 + q) ^ l16) * 8));
#pragma unroll
      for (int ntk = 0; ntk < 4; ntk++)
        sres[ntk] = mfma_bf16(kf[ntk], qa[c], sres[ntk]);
    }

    const bool lastwin = (win == qt);
    short4v pa[4];
#pragma unroll
    for (int ntk = 0; ntk < 4; ntk++) {
#pragma unroll
      for (int rg = 0; rg < 4; rg++) {
        float e = __expf(sres[ntk][rg] * cSCALE);
        if (lastwin && (ntk * 16 + q * 4 + rg > wv * 16 + l16)) e = 0.f;
        lp += e;
        pa[ntk][rg] = (short)f2bf(e);
      }
    }

#pragma unroll
    for (int ntk = 0; ntk < 4; ntk++) {
#pragma unroll
      for (int db = 0; db < 8; db++) {
        short4v vb = *(const short4v*)(Vs + (db * 16 + l16) * 64 +
                       (((ntk * 2 + (q >> 1)) ^ (l16 & 7)) * 8 + (q & 1) * 4));
        oacc[db] = mfma_pv(pa[ntk], vb, oacc[db]);
      }
    }
  }

  float lf = lp;
  lf += __shfl_xor(lf, 16);
  lf += __shfl_xor(lf, 32);
  float li[4];
#pragma unroll
  for (int rg = 0; rg < 4; rg++) li[rg] = 1.0f / __shfl(lf, q * 4 + rg);

#pragma unroll
  for (int rg = 0; rg < 4; rg++) {
    int row = q0w + q * 4 + rg;
    unsigned short* dst = AO + (size_t)(bi * cS + row) * (cH * cHD) + h * cHD;
#pragma unroll
    for (int db = 0; db < 8; db++)
      dst[db * 16 + l16] = f2bf(oacc[db][rg] * li[rg]);
  }
}

// --------------------------- launch ----------------------------------------
extern "C" void kernel_launch(void* const* d_in, const int* in_sizes, int n_in,
                              void* d_out, int out_size, void* d_ws, size_t ws_size,
                              hipStream_t stream) {
  (void)in_sizes; (void)n_in; (void)out_size; (void)ws_size;
  char* ws = (char*)d_ws;
  size_t off = 0;
  auto alloc = [&](size_t bytes) -> char* {
    char* p = ws + off;
    off += (bytes + 255) & ~((size_t)255);
    return p;
  };
  int* flag            = (int*)alloc(256);
  float2* ropetab      = (float2*)alloc((size_t)cS * 64 * 8);
  float* nw            = (float*)alloc(256 * 4);
  float* scat          = (float*)alloc(4096 * 4);
  float* so            = (float*)alloc(2048 * 4);
  unsigned short* xp   = (unsigned short*)alloc((size_t)cM * cD * 2);      // packed x
  unsigned short* wp   = (unsigned short*)alloc((size_t)cNqkv * cD * 2);   // packed Wqkv
  unsigned short* wop  = (unsigned short*)alloc((size_t)cD * cH * cHD * 2);// packed Wo
  unsigned short* Qb   = (unsigned short*)alloc((size_t)cB * cH * cS * cHD * 2);
  unsigned short* Kb   = (unsigned short*)alloc((size_t)cB * cKVH * cS * cHD * 2);
  unsigned short* Vt   = (unsigned short*)alloc((size_t)cB * cKVH * cHD * cS * 2);
  unsigned short* AO   = (unsigned short*)alloc((size_t)cM * cD * 2);
  unsigned short* AOp  = (unsigned short*)alloc((size_t)cM * cD * 2);      // packed AO

  detect_dtype<<<1, 256, 0, stream>>>((const unsigned*)d_in[0], flag);

  // packers (fragment-order layout for register-streaming GEMMs)
  pack_frag<<<dim3(256, 8), 256, 0, stream>>>(d_in[0], xp, 2048, 0, flag);
  pack_frag<<<dim3(128, 8), 256, 0, stream>>>(d_in[1], wp, 2048, 2, flag);
  pack_frag<<<dim3(64, 8), 256, 0, stream>>>(d_in[3], wp + (size_t)128 * 64 * 512, 2048, 2, flag);
  pack_frag<<<dim3(64, 8), 256, 0, stream>>>(d_in[5], wp + (size_t)192 * 64 * 512, 2048, 2, flag);
  pack_frag<<<dim3(128, 8), 256, 0, stream>>>(d_in[7], wop, 2048, 2, flag);

  rope_pack<<<(cS * 64 + 255) / 256, 256, 0, stream>>>(d_in[11], d_in[12], ropetab, flag);
  conv_f32<<<1, 256, 0, stream>>>(d_in[9], nw, cHD, flag);
  conv_f32<<<1, 256, 0, stream>>>(d_in[10], nw + cHD, cHD, flag);
  conv_f32<<<8, 256, 0, stream>>>(d_in[2], scat, 2048, flag);
  conv_f32<<<4, 256, 0, stream>>>(d_in[4], scat + 2048, 1024, flag);
  conv_f32<<<4, 256, 0, stream>>>(d_in[6], scat + 3072, 1024, flag);
  conv_f32<<<8, 256, 0, stream>>>(d_in[8], so, 2048, flag);

  gemm_qkv<<<dim3(cNqkv / 128, cM / 128), 256, 0, stream>>>(
      xp, wp, scat, ropetab, nw, Qb, Kb, Vt);
  attn<<<dim3(cS / 64, cH, cB), 256, 0, stream>>>(Qb, Kb, Vt, AO);
  pack_frag<<<dim3(256, 8), 256, 0, stream>>>(AO, AOp, 2048, 3, flag);
  gemm_out<<<dim3(cD / 128, cM / 128), 256, 0, stream>>>(
      AOp, wop, so, d_out, flag, cD, (cH * cHD) / 32);
}

// Round 7
// 421.106 us; speedup vs baseline: 1.1822x; 1.1822x over previous
//
#include <hip/hip_runtime.h>

// ---------------------------------------------------------------------------
// QuantizedAttention: x[B,S,D] -> QKV proj (int8-quant wts) -> RMSNorm -> RoPE
//   -> causal GQA attention -> O proj.  B=2 S=2048 D=2048 H=16 KVH=8 HD=128.
// R7: (1) GEMM core: 4-phase register pipeline (32 outstanding loads/wave) to
// cover L2 latency; (2) attn epilogue writes O-proj A-fragments directly
// (deletes AO repack dispatch); (3) conv/pack dispatches merged (14 -> 9
// launches); (4) attn softmax in exp2 domain.
// ---------------------------------------------------------------------------

typedef __attribute__((ext_vector_type(4))) float floatx4;
typedef __attribute__((ext_vector_type(8))) short short8v;
typedef __attribute__((ext_vector_type(4))) short short4v;
typedef __attribute__((ext_vector_type(8))) unsigned short ushort8v;

#define DEVINL __device__ __forceinline__

constexpr int cB = 2, cS = 2048, cD = 2048, cH = 16, cKVH = 8, cHD = 128;
constexpr int cM = cB * cS;
constexpr int cNqkv = (cH + 2 * cKVH) * cHD;
constexpr float cEPS = 1e-6f;
// 1/sqrt(HD) * log2(e): softmax in base-2 domain (same softmax value).
constexpr float cSCL2 = 0.08838834764831845f * 1.4426950408889634f;

DEVINL unsigned short f2bf(float f) {
  unsigned u = __float_as_uint(f);
  unsigned r = ((u >> 16) & 1u) + 0x7FFFu;
  return (unsigned short)((u + r) >> 16);
}
DEVINL float bf2f(unsigned short h) { return __uint_as_float(((unsigned)h) << 16); }

DEVINL floatx4 mfma_bf16(short8v a, short8v b, floatx4 c) {
  return __builtin_amdgcn_mfma_f32_16x16x32_bf16(a, b, c, 0, 0, 0);
}

DEVINL floatx4 mfma_pv(short4v a, short4v b, floatx4 c) {
#if __has_builtin(__builtin_amdgcn_mfma_f32_16x16x16bf16_1k)
  return __builtin_amdgcn_mfma_f32_16x16x16bf16_1k(a, b, c, 0, 0, 0);
#else
  short8v a8 = {a[0], a[1], a[2], a[3], (short)0, (short)0, (short)0, (short)0};
  short8v b8 = {b[0], b[1], b[2], b[3], (short)0, (short)0, (short)0, (short)0};
  return __builtin_amdgcn_mfma_f32_16x16x32_bf16(a8, b8, c, 0, 0, 0);
#endif
}

DEVINL void gl_lds16(const void* g, void* l) {
  __builtin_amdgcn_global_load_lds(
      (const __attribute__((address_space(1))) void*)g,
      (__attribute__((address_space(3))) void*)l, 16, 0, 0);
}

// --------------------------- dtype detection -------------------------------
__global__ void detect_dtype(const unsigned* __restrict__ x, int* __restrict__ flag) {
  __shared__ int cnt;
  if (threadIdx.x == 0) cnt = 0;
  __syncthreads();
  int c = 0;
  for (int i = threadIdx.x; i < 4096; i += 256) {
    unsigned e = (x[i] >> 7) & 0xFFu;
    c += (e >= 100u && e <= 142u) ? 1 : 0;
  }
  atomicAdd(&cnt, c);
  __syncthreads();
  if (threadIdx.x == 0) *flag = (cnt > 2457) ? 1 : 0;  // 1 = host is bf16
}

// --------------------------- merged small conversions ----------------------
__global__ void conv_small(const void* p9, const void* p10, const void* p2,
                           const void* p4, const void* p6, const void* p8,
                           float* __restrict__ nw, float* __restrict__ scat,
                           float* __restrict__ so, const int* __restrict__ flag) {
  int i = blockIdx.x * 256 + threadIdx.x;
  int f = *flag;
  auto rd = [&](const void* p, int idx) -> float {
    return f ? bf2f(((const unsigned short*)p)[idx]) : ((const float*)p)[idx];
  };
  if (i < 256) {
    nw[i] = (i < 128) ? rd(p9, i) : rd(p10, i - 128);
  } else if (i < 256 + 4096) {
    int j = i - 256;
    scat[j] = (j < 2048) ? rd(p2, j) : (j < 3072 ? rd(p4, j - 2048) : rd(p6, j - 3072));
  } else if (i < 256 + 4096 + 2048) {
    int j = i - 4352;
    so[j] = rd(p8, j);
  }
}

// Packed RoPE table: tab[s*64+t] = {cos[s,t], sin[s,t]} (halves equal).
__global__ void rope_pack(const void* __restrict__ cosc, const void* __restrict__ sinc,
                          float2* __restrict__ tab, const int* __restrict__ flag) {
  int i = blockIdx.x * 256 + threadIdx.x;
  if (i >= cS * 64) return;
  int s = i >> 6, t = i & 63;
  int f = *flag;
  float c = f ? bf2f(((const unsigned short*)cosc)[s * cHD + t])
              : ((const float*)cosc)[s * cHD + t];
  float sn = f ? bf2f(((const unsigned short*)sinc)[s * cHD + t])
               : ((const float*)sinc)[s * cHD + t];
  tab[i] = make_float2(c, sn);
}

// --------------------------- fragment packers ------------------------------
// Fragment layout: dst[(T*64 + kb)*512 + lane*8 + j] =
//   src[T*16 + (lane&15)][kb*32 + (lane>>4)*8 + j]
DEVINL void pack_body(const void* src, unsigned short* dst, int K, int md,
                      int Trow, int Tdst, int kc, int tid, float L[16][264]) {
#pragma unroll
  for (int it = 0; it < 16; it++) {
    int e = it * 256 + tid;
    int r = e >> 8, c = e & 255;
    size_t idx = (size_t)(Trow * 16 + r) * K + kc * 256 + c;
    float v;
    if (md == 1)      v = ((const float*)src)[idx];
    else if (md == 2) v = (float)((const int*)src)[idx];
    else              v = bf2f(((const unsigned short*)src)[idx]);
    L[r][c] = v;
  }
  __syncthreads();
  const int lane = tid & 63, w = tid >> 6;
  const int q = lane >> 4, l16 = lane & 15;
#pragma unroll
  for (int p = 0; p < 2; p++) {
    int kbl = w + p * 4;
    ushort8v o;
#pragma unroll
    for (int j = 0; j < 8; j++) o[j] = f2bf(L[l16][kbl * 32 + q * 8 + j]);
    *(ushort8v*)(dst + ((size_t)Tdst * 64 + kc * 8 + kbl) * 512 + lane * 8) = o;
  }
}

__global__ __launch_bounds__(256) void pack_frag(
    const void* __restrict__ src, unsigned short* __restrict__ dst,
    int K, int mode, const int* __restrict__ flag) {
  __shared__ float L[16][264];
  int md = mode;
  if (md == 0) md = (*flag) ? 3 : 1;
  pack_body(src, dst, K, md, blockIdx.x, blockIdx.x, blockIdx.y, threadIdx.x, L);
}

// All three QKV weight tensors in one dispatch (T: 0..127 wq, 128..191 wk,
// 192..255 wv); dst layout continuous in T (matches gemm_qkv's Bp).
__global__ __launch_bounds__(256) void pack_wqkv(
    const int* __restrict__ wq, const int* __restrict__ wk,
    const int* __restrict__ wv, unsigned short* __restrict__ dst) {
  __shared__ float L[16][264];
  int T = blockIdx.x;
  const int* src;
  int Trow;
  if (T < 128)      { src = wq; Trow = T; }
  else if (T < 192) { src = wk; Trow = T - 128; }
  else              { src = wv; Trow = T - 192; }
  pack_body(src, dst, 2048, 2, Trow, T, blockIdx.y, threadIdx.x, L);
}

// --------------------- 4-phase register-streaming GEMM core ----------------
// Wave computes 64x64 (4x4 of 16x16x32 MFMA). 4 k-phases in flight (32
// outstanding global loads/wave) to cover L2 latency; no LDS, no barriers.
DEVINL void gemm_core4(const unsigned short* __restrict__ Ap,
                       const unsigned short* __restrict__ Bp,
                       int tm0, int tn0, int nkb, int lane,
                       floatx4 acc[4][4]) {
  const unsigned short* ap[4];
  const unsigned short* bp[4];
#pragma unroll
  for (int i = 0; i < 4; i++) {
    ap[i] = Ap + ((size_t)(tm0 + i) * 64) * 512 + lane * 8;
    bp[i] = Bp + ((size_t)(tn0 + i) * 64) * 512 + lane * 8;
  }
  short8v a[4][4], b[4][4];
#pragma unroll
  for (int p = 0; p < 4; p++)
#pragma unroll
    for (int i = 0; i < 4; i++) {
      a[p][i] = *(const short8v*)(ap[i] + p * 512);
      b[p][i] = *(const short8v*)(bp[i] + p * 512);
    }
  for (int kb = 0; kb < nkb; kb += 4) {
    const bool more = (kb + 4) < nkb;
#pragma unroll
    for (int p = 0; p < 4; p++) {
#pragma unroll
      for (int mt = 0; mt < 4; mt++)
#pragma unroll
        for (int nt = 0; nt < 4; nt++)
          acc[mt][nt] = mfma_bf16(a[p][mt], b[p][nt], acc[mt][nt]);
      if (more) {
        const int o = (kb + 4 + p) * 512;
#pragma unroll
        for (int i = 0; i < 4; i++) {
          a[p][i] = *(const short8v*)(ap[i] + o);
          b[p][i] = *(const short8v*)(bp[i] + o);
        }
      }
    }
  }
}

// ------------------- fused QKV GEMM + RMSNorm + RoPE + V^T -----------------
__global__ __launch_bounds__(256) void gemm_qkv(
    const unsigned short* __restrict__ Ap, const unsigned short* __restrict__ Bp,
    const float* __restrict__ colscale, const float2* __restrict__ ropetab,
    const float* __restrict__ nw, unsigned short* __restrict__ Qb,
    unsigned short* __restrict__ Kb, unsigned short* __restrict__ Vt) {
  __shared__ float4 smem4[2192];            // 35072 B (epilogue only)
  char* smem = (char*)smem4;
  const int tid = threadIdx.x;
  const int lane = tid & 63, wave = tid >> 6;
  const int q = lane >> 4, l16 = lane & 15;
  const int m0 = blockIdx.y * 128, n0 = blockIdx.x * 128;
  const int wm = (wave & 1) * 64, wn = (wave >> 1) * 64;

  floatx4 acc[4][4] = {};
  gemm_core4(Ap, Bp, (m0 + wm) >> 4, (n0 + wn) >> 4, cD / 32, lane, acc);

  float sc[4];
#pragma unroll
  for (int nt = 0; nt < 4; nt++) sc[nt] = colscale[n0 + wn + nt * 16 + l16];
#pragma unroll
  for (int mt = 0; mt < 4; mt++)
#pragma unroll
    for (int nt = 0; nt < 4; nt++)
#pragma unroll
      for (int rg = 0; rg < 4; rg++) acc[mt][nt][rg] *= sc[nt];

  const int tile_n = blockIdx.x;
  const int bi = m0 >> 11, sbase = m0 & (cS - 1);

  if (tile_n >= 24) {
    // V: transpose through LDS, store Vt[.,d,s]
    unsigned short* T = (unsigned short*)smem;   // [128 d][136 s]
#pragma unroll
    for (int mt = 0; mt < 4; mt++)
#pragma unroll
      for (int nt = 0; nt < 4; nt++) {
        short4v pk;
#pragma unroll
        for (int rg = 0; rg < 4; rg++) pk[rg] = (short)f2bf(acc[mt][nt][rg]);
        *(short4v*)(T + (wn + nt * 16 + l16) * 136 + (wm + mt * 16 + q * 4)) = pk;
      }
    __syncthreads();
    const int d = tid >> 1, sh = (tid & 1) * 64;
    unsigned short* dst = Vt + ((size_t)(bi * cKVH + (tile_n - 24)) * cHD + d) * cS
                          + sbase + sh;
#pragma unroll
    for (int j = 0; j < 8; j++)
      *(ushort8v*)(dst + j * 8) = *(const ushort8v*)(T + d * 136 + sh + j * 8);
  } else {
    // Q/K: RMSNorm + RoPE
    unsigned short* W = (unsigned short*)smem;   // 4 waves x 4096 ushorts
    float* ssq  = (float*)(smem + 32768);        // [2][128]
    float* invs = (float*)(smem + 33792);        // [128]

    float sl[4][4];
#pragma unroll
    for (int mt = 0; mt < 4; mt++)
#pragma unroll
      for (int rg = 0; rg < 4; rg++) {
        float s = 0.f;
#pragma unroll
        for (int nt = 0; nt < 4; nt++) s += acc[mt][nt][rg] * acc[mt][nt][rg];
        s += __shfl_xor(s, 1); s += __shfl_xor(s, 2);
        s += __shfl_xor(s, 4); s += __shfl_xor(s, 8);
        sl[mt][rg] = s;
      }
    unsigned short* Wo = W + wave * 4096;
#pragma unroll
    for (int mt = 0; mt < 4; mt++)
#pragma unroll
      for (int nt = 0; nt < 4; nt++) {
        short4v pk;
#pragma unroll
        for (int rg = 0; rg < 4; rg++) pk[rg] = (short)f2bf(acc[mt][nt][rg]);
        *(short4v*)(Wo + (mt * 4 + nt) * 256 + lane * 4) = pk;
      }
    if (l16 == 0) {
#pragma unroll
      for (int mt = 0; mt < 4; mt++)
#pragma unroll
        for (int rg = 0; rg < 4; rg++)
          ssq[((wave >> 1) & 1) * 128 + wm + mt * 16 + q * 4 + rg] = sl[mt][rg];
    }
    __syncthreads();
    if (tid < 128)
      invs[tid] = rsqrtf((ssq[tid] + ssq[128 + tid]) * (1.0f / cHD) + cEPS);
    __syncthreads();

    const unsigned short* Wp = W + (wave ^ 2) * 4096;
    const int wn1 = wave >> 1;
    const float* nwb = nw + (tile_n < 16 ? 0 : cHD);
    float wown[4], wpar[4];
#pragma unroll
    for (int nt = 0; nt < 4; nt++) {
      wown[nt] = nwb[wn1 * 64 + nt * 16 + l16];
      wpar[nt] = nwb[(wn1 ^ 1) * 64 + nt * 16 + l16];
    }
    unsigned short* dstb = (tile_n < 16)
        ? Qb + ((size_t)(bi * cH + tile_n) * cS) * cHD
        : Kb + ((size_t)(bi * cKVH + (tile_n - 16)) * cS) * cHD;
#pragma unroll
    for (int mt = 0; mt < 4; mt++) {
      float iv[4];
#pragma unroll
      for (int rg = 0; rg < 4; rg++) iv[rg] = invs[wm + mt * 16 + q * 4 + rg];
#pragma unroll
      for (int nt = 0; nt < 4; nt++) {
        short4v pk = *(const short4v*)(Wp + (mt * 4 + nt) * 256 + lane * 4);
#pragma unroll
        for (int rg = 0; rg < 4; rg++) {
          int srow = sbase + wm + mt * 16 + q * 4 + rg;
          float2 cs = ropetab[srow * 64 + nt * 16 + l16];
          float nown = acc[mt][nt][rg] * iv[rg] * wown[nt];
          float npar = bf2f((unsigned short)pk[rg]) * iv[rg] * wpar[nt];
          float o = wn1 == 0 ? nown * cs.x - npar * cs.y
                             : nown * cs.x + npar * cs.y;
          dstb[(size_t)srow * cHD + wn1 * 64 + nt * 16 + l16] = f2bf(o);
        }
      }
    }
  }
}

// ------------------- O-proj GEMM with fused flag-output --------------------
__global__ __launch_bounds__(256) void gemm_out(
    const unsigned short* __restrict__ Ap, const unsigned short* __restrict__ Bp,
    const float* __restrict__ colscale, void* __restrict__ Cout,
    const int* __restrict__ flag, int N, int nkb) {
  const int tid = threadIdx.x;
  const int lane = tid & 63, wave = tid >> 6;
  const int q = lane >> 4, l16 = lane & 15;
  const int m0 = blockIdx.y * 128, n0 = blockIdx.x * 128;
  const int wm = (wave & 1) * 64, wn = (wave >> 1) * 64;

  floatx4 acc[4][4] = {};
  gemm_core4(Ap, Bp, (m0 + wm) >> 4, (n0 + wn) >> 4, nkb, lane, acc);

  const int f = *flag;
#pragma unroll
  for (int mt = 0; mt < 4; mt++) {
    int r0 = m0 + wm + mt * 16 + q * 4;
#pragma unroll
    for (int nt = 0; nt < 4; nt++) {
      int cn = n0 + wn + nt * 16 + l16;
      float sc = colscale[cn];
#pragma unroll
      for (int rg = 0; rg < 4; rg++) {
        float v = acc[mt][nt][rg] * sc;
        if (f) ((unsigned short*)Cout)[(size_t)(r0 + rg) * N + cn] = f2bf(v);
        else   ((float*)Cout)[(size_t)(r0 + rg) * N + cn] = v;
      }
    }
  }
}

// --------------------------- flash attention (v5) --------------------------
// R4 structure (q-split waves, no-max softmax, S^T layout, global_load_lds +
// XOR swizzle + double buffer) + exp2-domain softmax + epilogue writing the
// O-projection A-fragments directly (packed AOp; kills the repack dispatch).
__global__ __launch_bounds__(256, 2) void attn(
    const unsigned short* __restrict__ Qb, const unsigned short* __restrict__ Kb,
    const unsigned short* __restrict__ Vt, unsigned short* __restrict__ AOp) {
  __shared__ unsigned short SM[32768];
  const int tid = threadIdx.x;
  const int lane = tid & 63, wv = tid >> 6;
  const int q = lane >> 4, l16 = lane & 15;
  const int bi = blockIdx.z, h = blockIdx.y;
  const int kh = h >> 1;
  const int qt = (int)gridDim.x - 1 - (int)blockIdx.x;   // LPT
  const int q0 = qt * 64;
  const int q0w = q0 + wv * 16;

  const unsigned short* Qbase = Qb + ((size_t)(bi * cH + h) * cS + q0w) * cHD;
  const unsigned short* Kbase = Kb + ((size_t)(bi * cKVH + kh) * cS) * cHD;
  const unsigned short* Vbase = Vt + ((size_t)(bi * cKVH + kh) * cHD) * cS;

  short8v qa[4];
#pragma unroll
  for (int c = 0; c < 4; c++)
    qa[c] = *(const short8v*)(Qbase + (size_t)l16 * cHD + c * 32 + q * 8);

  floatx4 oacc[8] = {};
  float lp = 0.f;

  int koff[4], voff[4];
#pragma unroll
  for (int i = 0; i < 4; i++) {
    int s = (wv * 4 + i) * 64 + lane;
    int r = s >> 4, u = (s & 15) ^ (r & 15);
    koff[i] = r * cHD + u * 8;
    int d = s >> 3, uv = (s & 7) ^ (d & 7);
    voff[i] = d * cS + uv * 8;
  }

  auto stage = [&](int win) {
    const int buf = (win & 1) * 16384;
    const int kv0 = win * 64;
    unsigned short* Kdst = SM + buf + (wv * 4) * 512;
    unsigned short* Vdst = SM + buf + 8192 + (wv * 4) * 512;
#pragma unroll
    for (int i = 0; i < 4; i++)
      gl_lds16(Kbase + (size_t)kv0 * cHD + koff[i], Kdst + i * 512);
#pragma unroll
    for (int i = 0; i < 4; i++)
      gl_lds16(Vbase + (size_t)kv0 + voff[i], Vdst + i * 512);
  };

  stage(0);
  for (int win = 0; win <= qt; win++) {
    __syncthreads();
    if (win < qt) stage(win + 1);
    const unsigned short* Ks = SM + (win & 1) * 16384;
    const unsigned short* Vs = Ks + 8192;

    floatx4 sres[4] = {};
#pragma unroll
    for (int c = 0; c < 4; c++) {
      short8v kf[4];
#pragma unroll
      for (int ntk = 0; ntk < 4; ntk++)
        kf[ntk] = *(const short8v*)(Ks + (ntk * 16 + l16) * 128 + (((c * 4 + q) ^ l16) * 8));
#pragma unroll
      for (int ntk = 0; ntk < 4; ntk++)
        sres[ntk] = mfma_bf16(kf[ntk], qa[c], sres[ntk]);
    }

    const bool lastwin = (win == qt);
    short4v pa[4];
#pragma unroll
    for (int ntk = 0; ntk < 4; ntk++) {
#pragma unroll
      for (int rg = 0; rg < 4; rg++) {
        float e = exp2f(sres[ntk][rg] * cSCL2);
        if (lastwin && (ntk * 16 + q * 4 + rg > wv * 16 + l16)) e = 0.f;
        lp += e;
        pa[ntk][rg] = (short)f2bf(e);
      }
    }

#pragma unroll
    for (int ntk = 0; ntk < 4; ntk++) {
#pragma unroll
      for (int db = 0; db < 8; db++) {
        short4v vb = *(const short4v*)(Vs + (db * 16 + l16) * 64 +
                       (((ntk * 2 + (q >> 1)) ^ (l16 & 7)) * 8 + (q & 1) * 4));
        oacc[db] = mfma_pv(pa[ntk], vb, oacc[db]);
      }
    }
  }

  float lf = lp;
  lf += __shfl_xor(lf, 16);
  lf += __shfl_xor(lf, 32);
  float li[4];
#pragma unroll
  for (int rg = 0; rg < 4; rg++) li[rg] = 1.0f / __shfl(lf, q * 4 + rg);

  // ---- epilogue: O (C-layout) -> LDS transpose -> packed A-fragments ----
  __syncthreads();                     // all waves done reading staging LDS
  unsigned short* T = SM + wv * 16 * 136;   // per-wave [16 s][136 d]
#pragma unroll
  for (int rg = 0; rg < 4; rg++)
#pragma unroll
    for (int db = 0; db < 8; db++)
      T[(q * 4 + rg) * 136 + db * 16 + l16] = f2bf(oacc[db][rg] * li[rg]);
  // wave-private region; same-wave LDS ops are ordered -> no barrier
  const int mtile = (bi * cS + q0w) >> 4;
#pragma unroll
  for (int kbl = 0; kbl < 4; kbl++) {
    short8v fr = *(const short8v*)(T + l16 * 136 + kbl * 32 + q * 8);
    *(short8v*)(AOp + ((size_t)mtile * 64 + h * 4 + kbl) * 512 + lane * 8) = fr;
  }
}

// --------------------------- launch ----------------------------------------
extern "C" void kernel_launch(void* const* d_in, const int* in_sizes, int n_in,
                              void* d_out, int out_size, void* d_ws, size_t ws_size,
                              hipStream_t stream) {
  (void)in_sizes; (void)n_in; (void)out_size; (void)ws_size;
  char* ws = (char*)d_ws;
  size_t off = 0;
  auto alloc = [&](size_t bytes) -> char* {
    char* p = ws + off;
    off += (bytes + 255) & ~((size_t)255);
    return p;
  };
  int* flag            = (int*)alloc(256);
  float2* ropetab      = (float2*)alloc((size_t)cS * 64 * 8);
  float* nw            = (float*)alloc(256 * 4);
  float* scat          = (float*)alloc(4096 * 4);
  float* so            = (float*)alloc(2048 * 4);
  unsigned short* xp   = (unsigned short*)alloc((size_t)cM * cD * 2);
  unsigned short* wp   = (unsigned short*)alloc((size_t)cNqkv * cD * 2);
  unsigned short* wop  = (unsigned short*)alloc((size_t)cD * cH * cHD * 2);
  unsigned short* Qb   = (unsigned short*)alloc((size_t)cB * cH * cS * cHD * 2);
  unsigned short* Kb   = (unsigned short*)alloc((size_t)cB * cKVH * cS * cHD * 2);
  unsigned short* Vt   = (unsigned short*)alloc((size_t)cB * cKVH * cHD * cS * 2);
  unsigned short* AOp  = (unsigned short*)alloc((size_t)cM * cD * 2);

  detect_dtype<<<1, 256, 0, stream>>>((const unsigned*)d_in[0], flag);
  conv_small<<<25, 256, 0, stream>>>(d_in[9], d_in[10], d_in[2], d_in[4], d_in[6],
                                     d_in[8], nw, scat, so, flag);
  rope_pack<<<(cS * 64 + 255) / 256, 256, 0, stream>>>(d_in[11], d_in[12], ropetab, flag);
  pack_frag<<<dim3(256, 8), 256, 0, stream>>>(d_in[0], xp, 2048, 0, flag);
  pack_wqkv<<<dim3(256, 8), 256, 0, stream>>>((const int*)d_in[1], (const int*)d_in[3],
                                              (const int*)d_in[5], wp);
  pack_frag<<<dim3(128, 8), 256, 0, stream>>>(d_in[7], wop, 2048, 2, flag);

  gemm_qkv<<<dim3(cNqkv / 128, cM / 128), 256, 0, stream>>>(
      xp, wp, scat, ropetab, nw, Qb, Kb, Vt);
  attn<<<dim3(cS / 64, cH, cB), 256, 0, stream>>>(Qb, Kb, Vt, AOp);
  gemm_out<<<dim3(cD / 128, cM / 128), 256, 0, stream>>>(
      AOp, wop, so, d_out, flag, cD, (cH * cHD) / 32);
}